// Round 6
// baseline (452.684 us; speedup 1.0000x reference)
//
#include <hip/hip_runtime.h>
#include <hip/hip_bf16.h>

typedef __attribute__((ext_vector_type(8))) short short8;
typedef __attribute__((ext_vector_type(4))) float f32x4;

#define LN_EPS 1e-5f

__device__ __forceinline__ unsigned short f2bf(float f) {
  union { float f; unsigned u; } v; v.f = f;
  unsigned r = v.u + 0x7FFFu + ((v.u >> 16) & 1u);
  return (unsigned short)(r >> 16);
}

// x: (2, 96, 32, 128, 128) f32 ; w: (192, 768) f32 ; out: (2, 192, 16, 64, 64) f32
// k' = (dd*2+hh)*192 + c*2 + ww   (orig k = (dd*2+hh)*192 + ww*96 + c)
// Weights pre-swizzled to MFMA B-frag order: [NT(12)][ks(24)][lane(64)][8 bf16]

__global__ __launch_bounds__(256) void pm_prep(
    const float* __restrict__ w, const float* __restrict__ g,
    const float* __restrict__ be, unsigned short* __restrict__ wg,
    float* __restrict__ sb) {
  const int o = blockIdx.x;
  const int t = threadIdx.x;
  __shared__ float red[256][2];
  float sa = 0.f, ba = 0.f;
#pragma unroll
  for (int u = 0; u < 3; ++u) {
    int kp = t + 256 * u;
    int dh = kp / 192;
    int rem = kp - dh * 192;
    int c = rem >> 1, ww = rem & 1;
    int k = dh * 192 + ww * 96 + c;
    float wv = w[o * 768 + k];
    float v = wv * g[k];
    sa += v;
    ba += wv * be[k];
    int NT = o >> 4, ks = kp >> 5, qq = (kp >> 3) & 3, jj = kp & 7;
    wg[(((NT * 24 + ks) * 64) + qq * 16 + (o & 15)) * 8 + jj] = f2bf(v);
  }
  red[t][0] = sa; red[t][1] = ba;
  __syncthreads();
  for (int s = 128; s > 0; s >>= 1) {
    if (t < s) { red[t][0] += red[t + s][0]; red[t][1] += red[t + s][1]; }
    __syncthreads();
  }
  if (t == 0) { sb[o] = red[0][0]; sb[192 + o] = red[0][1]; }
}

// One wave per block; wave owns M=16 output positions x all 192 outputs.
// A-fragments loaded directly from global in MFMA frag layout; no LDS, no barriers.
__global__ __launch_bounds__(64, 3) void pm_main(
    const float* __restrict__ x, const unsigned short* __restrict__ wg,
    const float* __restrict__ sb, float* __restrict__ out) {
  const int bid = blockIdx.x;       // 8192 = (b, d2, h2, wq)
  const int wq = bid & 3;           // 16-wide quarter of W2
  const int h2 = (bid >> 2) & 63;
  const int d2 = (bid >> 8) & 15;
  const int b = bid >> 12;
  const int lane = threadIdx.x;     // 0..63
  const int al = lane & 15, ah = lane >> 4;   // row (=w2 pos), k-octet

  // lane's global base: w = 2*w2 = wq*32 + 2*al, channel base ah*4
  const float* xb = x + (size_t)b * (96 * 32 * 128 * 128) + wq * 32 + 2 * al;

  float ssum = 0.f, ssq = 0.f;   // partial LN sums for row al (k-octets ah, all phases)

  f32x4 acc[12];
#pragma unroll
  for (int nt = 0; nt < 12; ++nt) acc[nt] = {0.f, 0.f, 0.f, 0.f};

  const short8* wgs = (const short8*)wg;

#pragma unroll
  for (int p = 0; p < 4; ++p) {
    const int off = (2 * d2 + (p >> 1)) * 16384 + (2 * h2 + (p & 1)) * 128;
    // ---- issue all 24 A-loads for this phase (frag layout, 128B coalesced/16 lanes)
    float2 raw[6][4];
#pragma unroll
    for (int ksl = 0; ksl < 6; ++ksl)
#pragma unroll
      for (int i = 0; i < 4; ++i) {
        int c = ksl * 16 + ah * 4 + i;
        raw[ksl][i] = *(const float2*)(xb + (size_t)c * 524288 + off);
      }
    // ---- convert to bf16 frags + fold LN partials (raw regs die here)
    short8 afr[6];
#pragma unroll
    for (int ksl = 0; ksl < 6; ++ksl)
#pragma unroll
      for (int i = 0; i < 4; ++i) {
        float2 f = raw[ksl][i];
        ssum += f.x + f.y;
        ssq += f.x * f.x + f.y * f.y;
        afr[ksl][2 * i] = (short)f2bf(f.x);
        afr[ksl][2 * i + 1] = (short)f2bf(f.y);
      }
    // ---- GEMM across all 12 n-tiles, 2-deep B lookahead (window 3x6 frags)
    const int ks0 = p * 6;
    short8 Bw[3][6];
#pragma unroll
    for (int k = 0; k < 6; ++k) Bw[0][k] = wgs[(0 * 24 + ks0 + k) * 64 + lane];
#pragma unroll
    for (int k = 0; k < 6; ++k) Bw[1][k] = wgs[(1 * 24 + ks0 + k) * 64 + lane];
#pragma unroll
    for (int nt = 0; nt < 12; ++nt) {
      if (nt + 2 < 12) {
#pragma unroll
        for (int k = 0; k < 6; ++k)
          Bw[(nt + 2) % 3][k] = wgs[((nt + 2) * 24 + ks0 + k) * 64 + lane];
      }
#pragma unroll
      for (int k = 0; k < 6; ++k)
        acc[nt] = __builtin_amdgcn_mfma_f32_16x16x32_bf16(afr[k], Bw[nt % 3][k], acc[nt], 0, 0, 0);
    }
  }

  // ---- LN stats: reduce over the 4 k-octet lanes of each row
  ssum += __shfl_xor(ssum, 16); ssum += __shfl_xor(ssum, 32);
  ssq  += __shfl_xor(ssq, 16);  ssq  += __shfl_xor(ssq, 32);
  float mu = ssum * (1.f / 768.f);
  float var = ssq * (1.f / 768.f) - mu * mu;
  float rs = rsqrtf(var + LN_EPS);
  float murs = mu * rs;
  // lane holds stats of row al; epilogue needs rows 4*ah..4*ah+3
  float rs4[4], mr4[4];
#pragma unroll
  for (int j = 0; j < 4; ++j) {
    rs4[j] = __shfl(rs, 4 * ah + j);
    mr4[j] = __shfl(murs, 4 * ah + j);
  }

  // ---- epilogue: y = rs*acc - (mu*rs)*S[o] + bias[o]
#pragma unroll
  for (int nt = 0; nt < 12; ++nt) {
    int o = nt * 16 + al;
    float Sv = sb[o], Bv = sb[192 + o];
    float* ob = out + (((size_t)(b * 192 + o) * 16 + d2) * 64 + h2) * 64 + wq * 16 + ah * 4;
    float4 y;
    y.x = rs4[0] * acc[nt][0] - mr4[0] * Sv + Bv;
    y.y = rs4[1] * acc[nt][1] - mr4[1] * Sv + Bv;
    y.z = rs4[2] * acc[nt][2] - mr4[2] * Sv + Bv;
    y.w = rs4[3] * acc[nt][3] - mr4[3] * Sv + Bv;
    *(float4*)ob = y;
  }
}

extern "C" void kernel_launch(void* const* d_in, const int* in_sizes, int n_in,
                              void* d_out, int out_size, void* d_ws, size_t ws_size,
                              hipStream_t stream) {
  (void)in_sizes; (void)n_in; (void)out_size; (void)ws_size;
  const float* x  = (const float*)d_in[0];
  const float* w  = (const float*)d_in[1];
  const float* g  = (const float*)d_in[2];
  const float* be = (const float*)d_in[3];
  unsigned short* wg = (unsigned short*)d_ws;
  float* sb = (float*)((char*)d_ws + 192 * 768 * sizeof(unsigned short));
  pm_prep<<<192, 256, 0, stream>>>(w, g, be, wg, sb);
  pm_main<<<8192, 64, 0, stream>>>(x, wg, sb, (float*)d_out);
}

// Round 7
// 156.505 us; speedup vs baseline: 2.8925x; 2.8925x over previous
//
#include <hip/hip_runtime.h>
#include <hip/hip_bf16.h>

typedef __attribute__((ext_vector_type(8))) short short8;
typedef __attribute__((ext_vector_type(4))) float f32x4;

#define LN_EPS 1e-5f

__device__ __forceinline__ unsigned short f2bf(float f) {
  union { float f; unsigned u; } v; v.f = f;
  unsigned r = v.u + 0x7FFFu + ((v.u >> 16) & 1u);
  return (unsigned short)(r >> 16);
}

// HW round-to-nearest-even f32 pair -> packed bf16x2 (low=a, high=b)
__device__ __forceinline__ unsigned cvt_pk_bf16(float a, float b) {
  unsigned r;
  asm("v_cvt_pk_bf16_f32 %0, %1, %2" : "=v"(r) : "v"(a), "v"(b));
  return r;
}

// Swizzled byte address into A tile: row in [0,32), colb in [0,1536) bytes.
__device__ __forceinline__ int a_addr(int row, int colb) {
  return row * 1536 + (colb ^ ((row & 7) << 4));
}

// x: (2, 96, 32, 128, 128) f32 ; w: (192, 768) f32 ; out: (2, 192, 16, 64, 64) f32
// k' = (dd*2+hh)*192 + c*2 + ww   (orig k = (dd*2+hh)*192 + ww*96 + c)
// Weights pre-swizzled to MFMA B-frag order: [NT(12)][ks(24)][lane(64)][8 bf16]

__global__ __launch_bounds__(256) void pm_prep(
    const float* __restrict__ w, const float* __restrict__ g,
    const float* __restrict__ be, unsigned short* __restrict__ wg,
    float* __restrict__ sb) {
  const int o = blockIdx.x;
  const int t = threadIdx.x;
  const int lane = t & 63, wv = t >> 6;
  __shared__ float red[4][2];
  float sa = 0.f, ba = 0.f;
#pragma unroll
  for (int u = 0; u < 3; ++u) {
    int kp = t + 256 * u;
    int dh = kp / 192;
    int rem = kp - dh * 192;
    int c = rem >> 1, ww = rem & 1;
    int k = dh * 192 + ww * 96 + c;
    float wv_ = w[o * 768 + k];
    float v = wv_ * g[k];
    sa += v;
    ba += wv_ * be[k];
    int NT = o >> 4, ks = kp >> 5, qq = (kp >> 3) & 3, jj = kp & 7;
    wg[(((NT * 24 + ks) * 64) + qq * 16 + (o & 15)) * 8 + jj] = f2bf(v);
  }
#pragma unroll
  for (int d = 1; d < 64; d <<= 1) {
    sa += __shfl_xor(sa, d);
    ba += __shfl_xor(ba, d);
  }
  if (lane == 0) { red[wv][0] = sa; red[wv][1] = ba; }
  __syncthreads();
  if (t == 0) {
    sb[o] = red[0][0] + red[1][0] + red[2][0] + red[3][0];
    sb[192 + o] = red[0][1] + red[1][1] + red[2][1] + red[3][1];
  }
}

__global__ __launch_bounds__(256, 3) void pm_main(
    const float* __restrict__ x, const unsigned short* __restrict__ wg,
    const float* __restrict__ sb, float* __restrict__ out) {
  const int bid = blockIdx.x;       // 4096 = (b, d2, h2, wh)
  const int wh = bid & 1;
  const int h2 = (bid >> 1) & 63;
  const int d2 = (bid >> 7) & 15;
  const int b = bid >> 11;
  const int t = threadIdx.x;
  const int lane = t & 63, wv = t >> 6;
  const int q = lane & 15, sc = lane >> 4;

  __shared__ __align__(16) unsigned char A_lds[32 * 1536];  // 48 KB swizzled
  __shared__ float part[4][32][2];
  __shared__ float stats[32][2];

  const float* xb = x + (size_t)b * (96 * 32 * 128 * 128);
  const int cp0 = wv * 12 + sc * 3;          // channel-pair base for this lane
  const float* pc[3];
#pragma unroll
  for (int i = 0; i < 3; ++i)
    pc[i] = xb + (size_t)(2 * (cp0 + i)) * 524288 + wh * 64 + 4 * q;

  float sum0 = 0.f, sq0 = 0.f, sum1 = 0.f, sq1 = 0.f;
  float4 xa[3], xc[3];

  auto issue = [&](int p) {
    int off = (2 * d2 + (p >> 1)) * 16384 + (2 * h2 + (p & 1)) * 128;
#pragma unroll
    for (int i = 0; i < 3; ++i) {
      xa[i] = *(const float4*)(pc[i] + off);
      xc[i] = *(const float4*)(pc[i] + 524288 + off);
    }
  };

  auto consume = [&](int p) {
#pragma unroll
    for (int i = 0; i < 3; ++i) {
      float4 f0 = xa[i], f1 = xc[i];
      sum0 += (f0.x + f0.y) + (f1.x + f1.y);
      sq0  += f0.x * f0.x + f0.y * f0.y + f1.x * f1.x + f1.y * f1.y;
      sum1 += (f0.z + f0.w) + (f1.z + f1.w);
      sq1  += f0.z * f0.z + f0.w * f0.w + f1.z * f1.z + f1.w * f1.w;
      int colb = p * 384 + 8 * (cp0 + i);
      uint2 v0, v1;
      v0.x = cvt_pk_bf16(f0.x, f0.y); v0.y = cvt_pk_bf16(f1.x, f1.y);
      v1.x = cvt_pk_bf16(f0.z, f0.w); v1.y = cvt_pk_bf16(f1.z, f1.w);
      *(uint2*)&A_lds[a_addr(2 * q, colb)] = v0;       // m = 2q
      *(uint2*)&A_lds[a_addr(2 * q + 1, colb)] = v1;   // m = 2q+1
    }
  };

  const int al = lane & 15, ah = lane >> 4;
  const short8* wgs = (const short8*)wg;
  f32x4 acc[2][3];
#pragma unroll
  for (int mt = 0; mt < 2; ++mt)
#pragma unroll
    for (int nt = 0; nt < 3; ++nt) acc[mt][nt] = {0.f, 0.f, 0.f, 0.f};

  issue(0);

#pragma unroll
  for (int p = 0; p < 4; ++p) {
    consume(p);
    if (p == 3) {
      // reduce LN partials over sc (lane bits 4,5)
      sum0 += __shfl_xor(sum0, 16); sum0 += __shfl_xor(sum0, 32);
      sq0  += __shfl_xor(sq0, 16);  sq0  += __shfl_xor(sq0, 32);
      sum1 += __shfl_xor(sum1, 16); sum1 += __shfl_xor(sum1, 32);
      sq1  += __shfl_xor(sq1, 16);  sq1  += __shfl_xor(sq1, 32);
      if (sc == 0) {
        part[wv][2 * q][0] = sum0;     part[wv][2 * q][1] = sq0;
        part[wv][2 * q + 1][0] = sum1; part[wv][2 * q + 1][1] = sq1;
      }
    }
    __syncthreads();

    // B-fragments for this phase FIRST (in-order vmcnt: MFMA waits only on B)
    short8 bfr[6][3];
#pragma unroll
    for (int ksi = 0; ksi < 6; ++ksi)
#pragma unroll
      for (int nt = 0; nt < 3; ++nt)
        bfr[ksi][nt] = wgs[((wv * 3 + nt) * 24 + (p * 6 + ksi)) * 64 + lane];

    if (p < 3) issue(p + 1);  // next phase's x loads ride under the MFMAs

    if (p == 3) {
      int row = t & 31;
      float S = part[0][row][0] + part[1][row][0] + part[2][row][0] + part[3][row][0];
      float Q = part[0][row][1] + part[1][row][1] + part[2][row][1] + part[3][row][1];
      float mu = S * (1.f / 768.f);
      float var = Q * (1.f / 768.f) - mu * mu;
      float rs = rsqrtf(var + LN_EPS);
      stats[row][0] = rs;
      stats[row][1] = mu * rs;
    }

#pragma unroll
    for (int ksi = 0; ksi < 6; ++ksi) {
      int ks = p * 6 + ksi;
      short8 afr[2];
#pragma unroll
      for (int mt = 0; mt < 2; ++mt)
        afr[mt] = *(const short8*)&A_lds[a_addr(mt * 16 + al, ks * 64 + ah * 16)];
#pragma unroll
      for (int nt = 0; nt < 3; ++nt)
#pragma unroll
        for (int mt = 0; mt < 2; ++mt)
          acc[mt][nt] = __builtin_amdgcn_mfma_f32_16x16x32_bf16(afr[mt], bfr[ksi][nt], acc[mt][nt], 0, 0, 0);
    }
  }
  __syncthreads();

  // epilogue: y = rs*acc - (mu*rs)*S[o] + bias[o]
#pragma unroll
  for (int nt = 0; nt < 3; ++nt) {
    int o = wv * 48 + nt * 16 + al;
    float Sv = sb[o], Bv = sb[192 + o];
    float* ob = out + (((size_t)(b * 192 + o) * 16 + d2) * 64 + h2) * 64 + wh * 32;
#pragma unroll
    for (int mt = 0; mt < 2; ++mt) {
      int m0 = mt * 16 + ah * 4;
      float4 y;
      y.x = stats[m0 + 0][0] * acc[mt][nt][0] - stats[m0 + 0][1] * Sv + Bv;
      y.y = stats[m0 + 1][0] * acc[mt][nt][1] - stats[m0 + 1][1] * Sv + Bv;
      y.z = stats[m0 + 2][0] * acc[mt][nt][2] - stats[m0 + 2][1] * Sv + Bv;
      y.w = stats[m0 + 3][0] * acc[mt][nt][3] - stats[m0 + 3][1] * Sv + Bv;
      *(float4*)(ob + m0) = y;
    }
  }
}

extern "C" void kernel_launch(void* const* d_in, const int* in_sizes, int n_in,
                              void* d_out, int out_size, void* d_ws, size_t ws_size,
                              hipStream_t stream) {
  (void)in_sizes; (void)n_in; (void)out_size; (void)ws_size;
  const float* x  = (const float*)d_in[0];
  const float* w  = (const float*)d_in[1];
  const float* g  = (const float*)d_in[2];
  const float* be = (const float*)d_in[3];
  unsigned short* wg = (unsigned short*)d_ws;
  float* sb = (float*)((char*)d_ws + 192 * 768 * sizeof(unsigned short));
  pm_prep<<<192, 256, 0, stream>>>(w, g, be, wg, sb);
  pm_main<<<4096, 256, 0, stream>>>(x, wg, sb, (float*)d_out);
}